// Round 1
// baseline (1263.945 us; speedup 1.0000x reference)
//
#include <hip/hip_runtime.h>

#define DIMC 128

// ---------------------------------------------------------------- prep ----
__global__ void prep_kernel(const float* __restrict__ Wself,
                            const float* __restrict__ bvec,
                            float* __restrict__ Wsum,
                            float* __restrict__ bsum,
                            int nrel) {
    int i = blockIdx.x * blockDim.x + threadIdx.x;
    if (i < DIMC * DIMC) {
        float s = 0.f;
        for (int r = 0; r < nrel; ++r) s += Wself[r * DIMC * DIMC + i];
        Wsum[i] = s;
    }
    if (i < DIMC) {
        float s = 0.f;
        for (int r = 0; r < nrel; ++r) s += bvec[r * DIMC + i];
        bsum[i] = s;
    }
}

// ------------------------------------------------------------- scatter ----
// One 64-lane wave per edge; each lane atomically adds 2 floats (float2 of
// h[src]) into msg[rel][dst]. Lane 0 bumps deg.
__global__ void scatter_kernel(const float* __restrict__ h,
                               const int* __restrict__ src,
                               const int* __restrict__ dst,
                               float* __restrict__ msg,
                               float* __restrict__ deg,
                               int n, int E, int nrel) {
    long long gid = (long long)blockIdx.x * blockDim.x + threadIdx.x;
    long long eg = gid >> 6;
    int lane = (int)(gid & 63);
    long long total = (long long)nrel * E;
    if (eg >= total) return;
    int rel = (int)(eg / E);
    int e   = (int)(eg - (long long)rel * E);
    int s = src[(long long)rel * E + e];
    int d = dst[(long long)rel * E + e];
    const float2 hv = *(const float2*)&h[(long long)s * DIMC + lane * 2];
    float* mrow = msg + ((long long)rel * n + d) * DIMC + lane * 2;
    unsafeAtomicAdd(&mrow[0], hv.x);
    unsafeAtomicAdd(&mrow[1], hv.y);
    if (lane == 0) unsafeAtomicAdd(&deg[(long long)rel * n + d], 1.0f);
}

// ---------------------------------------------------------------- gemm ----
// out[32 rows x 128 cols] per block, 256 threads.
// Thread (c = tid&127, half = tid>>7) owns 16 rows of column c.
// Up to 4 (X, W) pairs: (h, Wsum) + 3 (mean_r, Wn_r). Mean = msg/deg folded
// into the LDS tile load. xs reads are wave-broadcast (free); wl reads are
// 64 consecutive dwords (2-way, free).
__global__ __launch_bounds__(256) void sage_gemm_kernel(
    const float* __restrict__ X0, const float* __restrict__ W0,
    const float* __restrict__ bsum,
    const float* __restrict__ m0, const float* __restrict__ d0, const float* __restrict__ Wn0,
    const float* __restrict__ m1, const float* __restrict__ d1, const float* __restrict__ Wn1,
    const float* __restrict__ m2, const float* __restrict__ d2, const float* __restrict__ Wn2,
    float* __restrict__ out, int n, int accum) {
    __shared__ float xs[32 * DIMC];   // 16 KB
    __shared__ float wl[64 * DIMC];   // 32 KB  -> 48 KB total, 3 blocks/CU

    const int tid  = threadIdx.x;
    const int c    = tid & 127;
    const int half = tid >> 7;
    const int row0 = blockIdx.x * 32;
    const int rb   = half * 16;

    float acc[16];
#pragma unroll
    for (int i = 0; i < 16; ++i) acc[i] = 0.f;

    const float* Xs[4] = {X0, m0, m1, m2};
    const float* Ds[4] = {nullptr, d0, d1, d2};
    const float* Ws[4] = {W0, Wn0, Wn1, Wn2};

#pragma unroll
    for (int mi = 0; mi < 4; ++mi) {
        const float* X = Xs[mi];
        if (X == nullptr) continue;
        const float* D = Ds[mi];
        const float* W = Ws[mi];

        __syncthreads();   // previous matrix's xs/wl reads complete
        // ---- load X tile [32][128], fold 1/max(deg,1) -----------------
#pragma unroll
        for (int v = 0; v < 4; ++v) {
            int f  = v * 1024 + tid * 4;
            int r  = f >> 7;
            int gr = row0 + r;
            float4 xv = make_float4(0.f, 0.f, 0.f, 0.f);
            if (gr < n) {
                xv = *(const float4*)&X[(long long)gr * DIMC + (f & 127)];
                if (D) {
                    float sc = 1.0f / fmaxf(D[gr], 1.0f);
                    xv.x *= sc; xv.y *= sc; xv.z *= sc; xv.w *= sc;
                }
            }
            *(float4*)&xs[f] = xv;
        }
        // ---- two 64-wide K tiles of W ---------------------------------
#pragma unroll
        for (int kt = 0; kt < 2; ++kt) {
            if (kt) __syncthreads();   // kt0 reads of wl complete
#pragma unroll
            for (int v = 0; v < 8; ++v) {
                int f = v * 1024 + tid * 4;
                *(float4*)&wl[f] = *(const float4*)&W[kt * 64 * DIMC + f];
            }
            __syncthreads();
#pragma unroll
            for (int k = 0; k < 64; k += 4) {
                float w0 = wl[(k + 0) * DIMC + c];
                float w1 = wl[(k + 1) * DIMC + c];
                float w2 = wl[(k + 2) * DIMC + c];
                float w3 = wl[(k + 3) * DIMC + c];
#pragma unroll
                for (int i = 0; i < 16; ++i) {
                    float4 xv = *(const float4*)&xs[(rb + i) * DIMC + kt * 64 + k];
                    acc[i] = fmaf(xv.x, w0, acc[i]);
                    acc[i] = fmaf(xv.y, w1, acc[i]);
                    acc[i] = fmaf(xv.z, w2, acc[i]);
                    acc[i] = fmaf(xv.w, w3, acc[i]);
                }
            }
        }
    }

    // ---- epilogue ----
    float bb = (X0 != nullptr) ? bsum[c] : 0.f;
#pragma unroll
    for (int i = 0; i < 16; ++i) {
        int gr = row0 + rb + i;
        if (gr < n) {
            long long idx = (long long)gr * DIMC + c;
            float v = acc[i] + bb;
            if (accum) v += out[idx];
            out[idx] = v;
        }
    }
}

// -------------------------------------------------------------- launch ----
extern "C" void kernel_launch(void* const* d_in, const int* in_sizes, int n_in,
                              void* d_out, int out_size, void* d_ws, size_t ws_size,
                              hipStream_t stream) {
    const float* h      = (const float*)d_in[0];
    const float* Wself  = (const float*)d_in[1];
    const float* Wneigh = (const float*)d_in[2];
    const float* b      = (const float*)d_in[3];
    const int*   esrc   = (const int*)d_in[4];
    const int*   edst   = (const int*)d_in[5];

    const int n    = in_sizes[0] / DIMC;
    const int nrel = in_sizes[1] / (DIMC * DIMC);
    const int E    = in_sizes[4] / nrel;

    float* out  = (float*)d_out;
    float* ws   = (float*)d_ws;
    float* Wsum = ws;
    float* bsum = ws + DIMC * DIMC;
    float* deg  = ws + DIMC * DIMC + DIMC;

    const size_t hdr = DIMC * DIMC + DIMC;
    const size_t needFused =
        (hdr + (size_t)nrel * n + (size_t)nrel * n * DIMC) * sizeof(float);
    const bool fused = (nrel == 3) && (ws_size >= needFused);

    prep_kernel<<<dim3((DIMC * DIMC + 255) / 256), dim3(256), 0, stream>>>(
        Wself, b, Wsum, bsum, nrel);

    const int gemmGrid = (n + 31) / 32;

    if (fused) {
        float* msg = deg + (size_t)nrel * n;
        hipMemsetAsync(deg, 0,
                       ((size_t)nrel * n + (size_t)nrel * n * DIMC) * sizeof(float),
                       stream);
        long long total = (long long)nrel * E * 64;
        scatter_kernel<<<dim3((unsigned)((total + 255) / 256)), dim3(256), 0, stream>>>(
            h, esrc, edst, msg, deg, n, E, nrel);
        sage_gemm_kernel<<<dim3(gemmGrid), dim3(256), 0, stream>>>(
            h, Wsum, bsum,
            msg,                        deg,         Wneigh,
            msg + (size_t)n * DIMC,     deg + n,     Wneigh + DIMC * DIMC,
            msg + 2 * (size_t)n * DIMC, deg + 2 * n, Wneigh + 2 * DIMC * DIMC,
            out, n, 0);
    } else {
        float* msg = deg + n;
        sage_gemm_kernel<<<dim3(gemmGrid), dim3(256), 0, stream>>>(
            h, Wsum, bsum,
            nullptr, nullptr, nullptr,
            nullptr, nullptr, nullptr,
            nullptr, nullptr, nullptr,
            out, n, 0);
        for (int r = 0; r < nrel; ++r) {
            hipMemsetAsync(deg, 0, ((size_t)n + (size_t)n * DIMC) * sizeof(float),
                           stream);
            long long total = (long long)E * 64;
            scatter_kernel<<<dim3((unsigned)((total + 255) / 256)), dim3(256), 0, stream>>>(
                h, esrc + (size_t)r * E, edst + (size_t)r * E, msg, deg, n, E, 1);
            sage_gemm_kernel<<<dim3(gemmGrid), dim3(256), 0, stream>>>(
                nullptr, nullptr, bsum,
                msg, deg, Wneigh + (size_t)r * DIMC * DIMC,
                nullptr, nullptr, nullptr,
                nullptr, nullptr, nullptr,
                out, n, 1);
        }
    }
}

// Round 2
// 216.696 us; speedup vs baseline: 5.8328x; 5.8328x over previous
//
#include <hip/hip_runtime.h>

#define DIMC 128
#define KCAT 512   // 128 * (1 self + 3 relations)

typedef __attribute__((ext_vector_type(8))) short bf16x8;
typedef __attribute__((ext_vector_type(4))) float f32x4;
typedef short short2v __attribute__((ext_vector_type(2)));

__device__ __forceinline__ unsigned short f2bf(float x) {
    unsigned u = __float_as_uint(x);
    u += 0x7fffu + ((u >> 16) & 1u);          // RNE
    return (unsigned short)(u >> 16);
}

__device__ __forceinline__ void gload_lds16(const void* g, void* l) {
    __builtin_amdgcn_global_load_lds(
        (const __attribute__((address_space(1))) void*)g,
        (__attribute__((address_space(3))) void*)l, 16, 0, 0);
}

__device__ __forceinline__ void atomic_pk_add_bf16(unsigned short* addr, unsigned int packed) {
#if __has_builtin(__builtin_amdgcn_global_atomic_fadd_v2bf16)
    union { unsigned int u; short2v v; } cv;
    cv.u = packed;
    __builtin_amdgcn_global_atomic_fadd_v2bf16(
        (__attribute__((address_space(1))) short2v*)addr, cv.v);
#else
    asm volatile("global_atomic_pk_add_bf16 %0, %1, off"
                 :: "v"((unsigned long long)(uintptr_t)addr), "v"(packed)
                 : "memory");
#endif
}

// ---------------------------------------------------------------- prep ----
// Wt[nn][k] (bf16, [128][512]): k<128 -> sum_r Wself[r][k][nn]; else Wneigh.
__global__ void prep_kernel(const float* __restrict__ Wself,
                            const float* __restrict__ Wneigh,
                            const float* __restrict__ b,
                            unsigned short* __restrict__ Wt,
                            float* __restrict__ bsum, int nrel) {
    int idx = blockIdx.x * blockDim.x + threadIdx.x;
    if (idx < DIMC * KCAT) {
        int k = idx & (KCAT - 1);
        int nn = idx >> 9;
        float v;
        if (k < DIMC) {
            v = 0.f;
            for (int r = 0; r < nrel; ++r) v += Wself[r * DIMC * DIMC + k * DIMC + nn];
        } else {
            int r = (k - DIMC) >> 7, kk = (k - DIMC) & 127;
            v = Wneigh[r * DIMC * DIMC + kk * DIMC + nn];
        }
        Wt[idx] = f2bf(v);
    }
    if (idx < DIMC) {
        float s = 0.f;
        for (int r = 0; r < nrel; ++r) s += b[r * DIMC + idx];
        bsum[idx] = s;
    }
}

// -------------------------------------------------------------- convth ----
// Xcat[r][0:128] = bf16(h[r]);  (msg columns are zeroed by memset)
__global__ void convth_kernel(const float* __restrict__ h,
                              unsigned short* __restrict__ Xcat, int n) {
    int idx = blockIdx.x * blockDim.x + threadIdx.x;
    if (idx >= n * 16) return;
    int r = idx >> 4, c = (idx & 15) << 3;
    const float4* hp = (const float4*)&h[(long long)r * DIMC + c];
    float4 a = hp[0], d = hp[1];
    union { unsigned short s[8]; uint4 v; } o;
    o.s[0] = f2bf(a.x); o.s[1] = f2bf(a.y); o.s[2] = f2bf(a.z); o.s[3] = f2bf(a.w);
    o.s[4] = f2bf(d.x); o.s[5] = f2bf(d.y); o.s[6] = f2bf(d.z); o.s[7] = f2bf(d.w);
    *(uint4*)(Xcat + (long long)r * KCAT + c) = o.v;
}

// -------------------------------------------------------------- degcnt ----
__global__ void degcnt_kernel(const int* __restrict__ edst,
                              float* __restrict__ deg, int n, int E) {
    int e = blockIdx.x * blockDim.x + threadIdx.x;
    int rel = blockIdx.y;
    if (e < E) unsafeAtomicAdd(&deg[(long long)rel * n + edst[(long long)rel * E + e]], 1.0f);
}

// ------------------------------------------------------------- scatter ----
// One 64-lane wave per edge; lane adds 2 scaled bf16 into Xcat's msg block.
__global__ void scatter_kernel(const float* __restrict__ h,
                               const int* __restrict__ esrc,
                               const int* __restrict__ edst,
                               const float* __restrict__ deg,
                               unsigned short* __restrict__ Xcat, int n, int E) {
    int t = blockIdx.x * blockDim.x + threadIdx.x;
    int eg = t >> 6, lane = t & 63;
    int rel = blockIdx.y;
    if (eg >= E) return;
    int s = esrc[(long long)rel * E + eg];
    int d = edst[(long long)rel * E + eg];
    float sc = 1.0f / fmaxf(deg[(long long)rel * n + d], 1.0f);
    const float2 hv = *(const float2*)&h[(long long)s * DIMC + lane * 2];
    unsigned p = (unsigned)f2bf(hv.x * sc) | ((unsigned)f2bf(hv.y * sc) << 16);
    atomic_pk_add_bf16(Xcat + (long long)d * KCAT + DIMC + rel * DIMC + lane * 2, p);
}

// ---------------------------------------------------------------- gemm ----
// out[Mpad x 128] = Xcat[Mpad x 512] @ Wt^T + bsum.  128x128 tile, BK=64,
// 4 waves (2x2), 16x16x32 bf16 MFMA, global_load_lds w/ pre-swizzled source.
__global__ __launch_bounds__(256) void mfma_gemm_kernel(
    const unsigned short* __restrict__ Xcat,
    const unsigned short* __restrict__ Wt,
    const float* __restrict__ bsum,
    float* __restrict__ out, int n) {
    __shared__ __align__(16) unsigned short As[128 * 64];
    __shared__ __align__(16) unsigned short Bs[128 * 64];

    const int tid = threadIdx.x;
    const int w   = tid >> 6;
    const int l   = tid & 63;
    const int wr  = w >> 1, wc = w & 1;
    const long long row0 = (long long)blockIdx.x * 128;

    const int lrow8 = l >> 3;                        // 0..7
    const int scol  = (((l & 7) ^ lrow8) << 4);      // pre-swizzled source col byte

    f32x4 zero4 = {0.f, 0.f, 0.f, 0.f};
    f32x4 acc[4][4];
#pragma unroll
    for (int m = 0; m < 4; ++m)
#pragma unroll
        for (int q = 0; q < 4; ++q) acc[m][q] = zero4;

    for (int kt = 0; kt < 8; ++kt) {
#pragma unroll
        for (int j = 0; j < 4; ++j) {
            int ch = w * 4 + j;                      // 1KB chunk 0..15
            int r  = ch * 8 + lrow8;                 // LDS/tile row this lane feeds
            gload_lds16((const char*)Xcat + (row0 + r) * (KCAT * 2) + kt * 128 + scol,
                        (char*)As + ch * 1024);
            gload_lds16((const char*)Wt + (long long)r * (KCAT * 2) + kt * 128 + scol,
                        (char*)Bs + ch * 1024);
        }
        __syncthreads();                             // drains vmcnt -> tiles ready

        bf16x8 af[4][2], bfr[4][2];
#pragma unroll
        for (int m = 0; m < 4; ++m)
#pragma unroll
            for (int ks = 0; ks < 2; ++ks) {
                int lr = wr * 64 + m * 16 + (l & 15);
                int cb = ks * 64 + ((l >> 4) << 4);
                af[m][ks] = *(const bf16x8*)((const char*)As + lr * 128 + (cb ^ ((lr & 7) << 4)));
                int br = wc * 64 + m * 16 + (l & 15);
                bfr[m][ks] = *(const bf16x8*)((const char*)Bs + br * 128 + (cb ^ ((br & 7) << 4)));
            }
#pragma unroll
        for (int m = 0; m < 4; ++m)
#pragma unroll
            for (int q = 0; q < 4; ++q)
#pragma unroll
                for (int ks = 0; ks < 2; ++ks)
                    acc[m][q] = __builtin_amdgcn_mfma_f32_16x16x32_bf16(
                        af[m][ks], bfr[q][ks], acc[m][q], 0, 0, 0);
        __syncthreads();                             // reads done before next stage
    }

#pragma unroll
    for (int q = 0; q < 4; ++q) {
        int ccol = wc * 64 + q * 16 + (l & 15);
        float bb = bsum[ccol];
#pragma unroll
        for (int m = 0; m < 4; ++m) {
            long long crow = row0 + wr * 64 + m * 16 + ((l >> 4) << 2);
#pragma unroll
            for (int j2 = 0; j2 < 4; ++j2) {
                long long gr = crow + j2;
                if (gr < n) out[gr * DIMC + ccol] = acc[m][q][j2] + bb;
            }
        }
    }
}

// -------------------------------------------------------------- launch ----
extern "C" void kernel_launch(void* const* d_in, const int* in_sizes, int n_in,
                              void* d_out, int out_size, void* d_ws, size_t ws_size,
                              hipStream_t stream) {
    const float* h      = (const float*)d_in[0];
    const float* Wself  = (const float*)d_in[1];
    const float* Wneigh = (const float*)d_in[2];
    const float* b      = (const float*)d_in[3];
    const int*   esrc   = (const int*)d_in[4];
    const int*   edst   = (const int*)d_in[5];

    const int n    = in_sizes[0] / DIMC;                 // 50000
    const int nrel = in_sizes[1] / (DIMC * DIMC);        // 3
    const int E    = in_sizes[4] / nrel;                 // 200000

    const int nblk = (n + 127) / 128;
    const int Mpad = nblk * 128;

    char* ws = (char*)d_ws;
    unsigned short* Xcat = (unsigned short*)ws;           // [Mpad][512] bf16
    size_t xbytes = (size_t)Mpad * KCAT * 2;
    float* deg = (float*)(ws + xbytes);                   // [nrel][n] f32
    size_t dbytes = (size_t)nrel * n * sizeof(float);
    unsigned short* Wt = (unsigned short*)(ws + xbytes + dbytes);   // [128][512] bf16
    float* bsum = (float*)(ws + xbytes + dbytes + (size_t)DIMC * KCAT * 2);

    hipMemsetAsync(ws, 0, xbytes + dbytes, stream);
    prep_kernel<<<dim3((DIMC * KCAT + 255) / 256), dim3(256), 0, stream>>>(
        Wself, Wneigh, b, Wt, bsum, nrel);
    convth_kernel<<<dim3((n * 16 + 255) / 256), dim3(256), 0, stream>>>(h, Xcat, n);
    degcnt_kernel<<<dim3((E + 255) / 256, nrel), dim3(256), 0, stream>>>(edst, deg, n, E);
    scatter_kernel<<<dim3((E * 64 + 255) / 256, nrel), dim3(256), 0, stream>>>(
        h, esrc, edst, deg, Xcat, n, E);
    mfma_gemm_kernel<<<dim3(nblk), dim3(256), 0, stream>>>(
        Xcat, Wt, bsum, (float*)d_out, n);
}

// Round 3
// 155.740 us; speedup vs baseline: 8.1157x; 1.3914x over previous
//
#include <hip/hip_runtime.h>

#define DIMC 128
#define KCAT 512   // 128 * (1 self + 3 relations)

typedef __attribute__((ext_vector_type(8))) short bf16x8;
typedef __attribute__((ext_vector_type(4))) float f32x4;

__device__ __forceinline__ unsigned short f2bf(float x) {
    unsigned u = __float_as_uint(x);
    u += 0x7fffu + ((u >> 16) & 1u);          // RNE
    return (unsigned short)(u >> 16);
}

__device__ __forceinline__ void gload_lds16(const void* g, void* l) {
    __builtin_amdgcn_global_load_lds(
        (const __attribute__((address_space(1))) void*)g,
        (__attribute__((address_space(3))) void*)l, 16, 0, 0);
}

// ---------------------------------------------------------------- prep ----
// Wt[nn][k] (bf16, [128][512]): k<128 -> sum_r Wself[r][k][nn]; else Wneigh.
__global__ void prep_kernel(const float* __restrict__ Wself,
                            const float* __restrict__ Wneigh,
                            const float* __restrict__ b,
                            unsigned short* __restrict__ Wt,
                            float* __restrict__ bsum, int nrel) {
    int idx = blockIdx.x * blockDim.x + threadIdx.x;
    if (idx < DIMC * KCAT) {
        int k = idx & (KCAT - 1);
        int nn = idx >> 9;
        float v;
        if (k < DIMC) {
            v = 0.f;
            for (int r = 0; r < nrel; ++r) v += Wself[r * DIMC * DIMC + k * DIMC + nn];
        } else {
            int r = (k - DIMC) >> 7, kk = (k - DIMC) & 127;
            v = Wneigh[r * DIMC * DIMC + kk * DIMC + nn];
        }
        Wt[idx] = f2bf(v);
    }
    if (idx < DIMC) {
        float s = 0.f;
        for (int r = 0; r < nrel; ++r) s += b[r * DIMC + idx];
        bsum[idx] = s;
    }
}

// -------------------------------------------------------------- convth ----
__global__ void convth_kernel(const float* __restrict__ h,
                              unsigned short* __restrict__ Xcat, int n) {
    int idx = blockIdx.x * blockDim.x + threadIdx.x;
    if (idx >= n * 16) return;
    int r = idx >> 4, c = (idx & 15) << 3;
    const float4* hp = (const float4*)&h[(long long)r * DIMC + c];
    float4 a = hp[0], d = hp[1];
    union { unsigned short s[8]; uint4 v; } o;
    o.s[0] = f2bf(a.x); o.s[1] = f2bf(a.y); o.s[2] = f2bf(a.z); o.s[3] = f2bf(a.w);
    o.s[4] = f2bf(d.x); o.s[5] = f2bf(d.y); o.s[6] = f2bf(d.z); o.s[7] = f2bf(d.w);
    *(uint4*)(Xcat + (long long)r * KCAT + c) = o.v;
}

// -------------------------------------------------------- CSR building ----
__global__ void degcnt_kernel(const int* __restrict__ edst,
                              int* __restrict__ counts, int n, int E) {
    int e = blockIdx.x * blockDim.x + threadIdx.x;
    int rel = blockIdx.y;
    if (e < E) atomicAdd(&counts[(long long)rel * n + edst[(long long)rel * E + e]], 1);
}

// Exclusive scan, stage 1: per-block (256) scan + block sums.
__global__ void scan_block_kernel(const int* __restrict__ counts,
                                  int* __restrict__ eprefix,
                                  int* __restrict__ bsums, int total) {
    __shared__ int lds[256];
    int i = blockIdx.x * 256 + threadIdx.x;
    int v = (i < total) ? counts[i] : 0;
    lds[threadIdx.x] = v;
    __syncthreads();
    for (int off = 1; off < 256; off <<= 1) {
        int t = (threadIdx.x >= off) ? lds[threadIdx.x - off] : 0;
        __syncthreads();
        lds[threadIdx.x] += t;
        __syncthreads();
    }
    if (i < total) eprefix[i] = lds[threadIdx.x] - v;    // exclusive
    if (threadIdx.x == 255) bsums[blockIdx.x] = lds[255];
}

// Stage 2: exclusive scan of block sums in place (nb <= 1024).
__global__ void scan_partials_kernel(int* __restrict__ bsums, int nb) {
    __shared__ int lds[1024];
    int v = (threadIdx.x < nb) ? bsums[threadIdx.x] : 0;
    lds[threadIdx.x] = v;
    __syncthreads();
    for (int off = 1; off < 1024; off <<= 1) {
        int t = (threadIdx.x >= off) ? lds[threadIdx.x - off] : 0;
        __syncthreads();
        lds[threadIdx.x] += t;
        __syncthreads();
    }
    if (threadIdx.x < nb) bsums[threadIdx.x] = lds[threadIdx.x] - v;
}

__global__ void fill_kernel(const int* __restrict__ esrc,
                            const int* __restrict__ edst,
                            const int* __restrict__ eprefix,
                            const int* __restrict__ boff,
                            int* __restrict__ cursor,
                            int* __restrict__ colidx, int n, int E) {
    int e = blockIdx.x * blockDim.x + threadIdx.x;
    int rel = blockIdx.y;
    if (e >= E) return;
    int d   = edst[(long long)rel * E + e];
    int idx = rel * n + d;
    int pos = eprefix[idx] + boff[idx >> 8] + atomicAdd(&cursor[idx], 1);
    colidx[pos] = esrc[(long long)rel * E + e];
}

// -------------------------------------------------------------- gather ----
// One wave per (rel,dst). Lane owns cols {2l, 2l+1}. Neighbor indices are
// loaded 64-per-chunk into lanes and broadcast via __shfl; h row reads are
// wave-coalesced 512B. f32 accumulate, scale by 1/deg, one bf16x2 store.
__global__ __launch_bounds__(256) void gather_kernel(
    const float* __restrict__ h,
    const int* __restrict__ counts,
    const int* __restrict__ eprefix,
    const int* __restrict__ boff,
    const int* __restrict__ colidx,
    unsigned short* __restrict__ Xcat, int n) {
    int w = threadIdx.x >> 6, lane = threadIdx.x & 63;
    int dst = blockIdx.x * 4 + w;
    int rel = blockIdx.y;
    if (dst >= n) return;
    int idx   = rel * n + dst;
    int deg   = counts[idx];
    int start = eprefix[idx] + boff[idx >> 8];

    float ax0 = 0.f, ay0 = 0.f, ax1 = 0.f, ay1 = 0.f;
    for (int base = 0; base < deg; base += 64) {
        int m = min(64, deg - base);
        int vidx = (lane < m) ? colidx[start + base + lane] : 0;
        int j = 0;
        for (; j + 1 < m; j += 2) {
            int s0 = __shfl(vidx, j);
            int s1 = __shfl(vidx, j + 1);
            float2 a = *(const float2*)&h[(long long)s0 * DIMC + lane * 2];
            float2 c = *(const float2*)&h[(long long)s1 * DIMC + lane * 2];
            ax0 += a.x; ay0 += a.y;
            ax1 += c.x; ay1 += c.y;
        }
        if (j < m) {
            int s0 = __shfl(vidx, j);
            float2 a = *(const float2*)&h[(long long)s0 * DIMC + lane * 2];
            ax0 += a.x; ay0 += a.y;
        }
    }
    float sc = (deg > 0) ? (1.0f / (float)deg) : 0.f;
    unsigned p = (unsigned)f2bf((ax0 + ax1) * sc) |
                 ((unsigned)f2bf((ay0 + ay1) * sc) << 16);
    *(unsigned*)(Xcat + (long long)dst * KCAT + DIMC + rel * DIMC + lane * 2) = p;
}

// ---------------------------------------------------------------- gemm ----
__global__ __launch_bounds__(256) void mfma_gemm_kernel(
    const unsigned short* __restrict__ Xcat,
    const unsigned short* __restrict__ Wt,
    const float* __restrict__ bsum,
    float* __restrict__ out, int n) {
    __shared__ __align__(16) unsigned short As[128 * 64];
    __shared__ __align__(16) unsigned short Bs[128 * 64];

    const int tid = threadIdx.x;
    const int w   = tid >> 6;
    const int l   = tid & 63;
    const int wr  = w >> 1, wc = w & 1;
    const long long row0 = (long long)blockIdx.x * 128;

    const int lrow8 = l >> 3;
    const int scol  = (((l & 7) ^ lrow8) << 4);

    f32x4 zero4 = {0.f, 0.f, 0.f, 0.f};
    f32x4 acc[4][4];
#pragma unroll
    for (int m = 0; m < 4; ++m)
#pragma unroll
        for (int q = 0; q < 4; ++q) acc[m][q] = zero4;

    for (int kt = 0; kt < 8; ++kt) {
#pragma unroll
        for (int j = 0; j < 4; ++j) {
            int ch = w * 4 + j;
            int r  = ch * 8 + lrow8;
            gload_lds16((const char*)Xcat + (row0 + r) * (KCAT * 2) + kt * 128 + scol,
                        (char*)As + ch * 1024);
            gload_lds16((const char*)Wt + (long long)r * (KCAT * 2) + kt * 128 + scol,
                        (char*)Bs + ch * 1024);
        }
        __syncthreads();

        bf16x8 af[4][2], bfr[4][2];
#pragma unroll
        for (int m = 0; m < 4; ++m)
#pragma unroll
            for (int ks = 0; ks < 2; ++ks) {
                int lr = wr * 64 + m * 16 + (l & 15);
                int cb = ks * 64 + ((l >> 4) << 4);
                af[m][ks] = *(const bf16x8*)((const char*)As + lr * 128 + (cb ^ ((lr & 7) << 4)));
                int br = wc * 64 + m * 16 + (l & 15);
                bfr[m][ks] = *(const bf16x8*)((const char*)Bs + br * 128 + (cb ^ ((br & 7) << 4)));
            }
#pragma unroll
        for (int m = 0; m < 4; ++m)
#pragma unroll
            for (int q = 0; q < 4; ++q)
#pragma unroll
                for (int ks = 0; ks < 2; ++ks)
                    acc[m][q] = __builtin_amdgcn_mfma_f32_16x16x32_bf16(
                        af[m][ks], bfr[q][ks], acc[m][q], 0, 0, 0);
        __syncthreads();
    }

#pragma unroll
    for (int q = 0; q < 4; ++q) {
        int ccol = wc * 64 + q * 16 + (l & 15);
        float bb = bsum[ccol];
#pragma unroll
        for (int m = 0; m < 4; ++m) {
            long long crow = row0 + wr * 64 + m * 16 + ((l >> 4) << 2);
#pragma unroll
            for (int j2 = 0; j2 < 4; ++j2) {
                long long gr = crow + j2;
                if (gr < n) out[gr * DIMC + ccol] = acc[m][q][j2] + bb;
            }
        }
    }
}

// -------------------------------------------------------------- launch ----
extern "C" void kernel_launch(void* const* d_in, const int* in_sizes, int n_in,
                              void* d_out, int out_size, void* d_ws, size_t ws_size,
                              hipStream_t stream) {
    const float* h      = (const float*)d_in[0];
    const float* Wself  = (const float*)d_in[1];
    const float* Wneigh = (const float*)d_in[2];
    const float* b      = (const float*)d_in[3];
    const int*   esrc   = (const int*)d_in[4];
    const int*   edst   = (const int*)d_in[5];

    const int n    = in_sizes[0] / DIMC;                 // 50000
    const int nrel = in_sizes[1] / (DIMC * DIMC);        // 3
    const int E    = in_sizes[4] / nrel;                 // 200000

    const int nblk = (n + 127) / 128;
    const int Mpad = nblk * 128;
    const int nseg = nrel * n;                           // 150000
    const int NB   = (nseg + 255) / 256;                 // scan blocks (<=1024)

    char* ws = (char*)d_ws;
    size_t off = 0;
    unsigned short* Xcat = (unsigned short*)(ws + off); off += (size_t)Mpad * KCAT * 2;
    unsigned short* Wt   = (unsigned short*)(ws + off); off += (size_t)DIMC * KCAT * 2;
    float* bsum          = (float*)(ws + off);          off += DIMC * sizeof(float);
    int* counts          = (int*)(ws + off);            off += (size_t)nseg * 4;
    int* cursor          = (int*)(ws + off);            off += (size_t)nseg * 4;
    int* eprefix         = (int*)(ws + off);            off += (size_t)nseg * 4;
    int* boff            = (int*)(ws + off);            off += 1024 * 4;
    int* colidx          = (int*)(ws + off);            off += (size_t)nrel * E * 4;

    // zero counts + cursor (contiguous)
    hipMemsetAsync(counts, 0, (size_t)nseg * 8, stream);

    prep_kernel<<<dim3((DIMC * KCAT + 255) / 256), dim3(256), 0, stream>>>(
        Wself, Wneigh, b, Wt, bsum, nrel);
    convth_kernel<<<dim3((n * 16 + 255) / 256), dim3(256), 0, stream>>>(h, Xcat, n);
    degcnt_kernel<<<dim3((E + 255) / 256, nrel), dim3(256), 0, stream>>>(
        edst, counts, n, E);
    scan_block_kernel<<<dim3(NB), dim3(256), 0, stream>>>(counts, eprefix, boff, nseg);
    scan_partials_kernel<<<dim3(1), dim3(1024), 0, stream>>>(boff, NB);
    fill_kernel<<<dim3((E + 255) / 256, nrel), dim3(256), 0, stream>>>(
        esrc, edst, eprefix, boff, cursor, colidx, n, E);
    gather_kernel<<<dim3((n + 3) / 4, nrel), dim3(256), 0, stream>>>(
        h, counts, eprefix, boff, colidx, Xcat, n);
    mfma_gemm_kernel<<<dim3(nblk), dim3(256), 0, stream>>>(
        Xcat, Wt, bsum, (float*)d_out, n);
}

// Round 4
// 143.926 us; speedup vs baseline: 8.7819x; 1.0821x over previous
//
#include <hip/hip_runtime.h>

#define DIMC 128
#define KCAT 512   // 128 * (1 self + 3 relations)

typedef __attribute__((ext_vector_type(8))) short bf16x8;
typedef __attribute__((ext_vector_type(4))) float f32x4;

__device__ __forceinline__ unsigned short f2bf(float x) {
    unsigned u = __float_as_uint(x);
    u += 0x7fffu + ((u >> 16) & 1u);          // RNE
    return (unsigned short)(u >> 16);
}

__device__ __forceinline__ void gload_lds16(const void* g, void* l) {
    __builtin_amdgcn_global_load_lds(
        (const __attribute__((address_space(1))) void*)g,
        (__attribute__((address_space(3))) void*)l, 16, 0, 0);
}

// bf16 pair (packed in u32) -> two floats
__device__ __forceinline__ void bf2x(unsigned u, float& lo, float& hi) {
    lo = __uint_as_float(u << 16);
    hi = __uint_as_float(u & 0xffff0000u);
}

// ---------------------------------------------------------------- prep ----
__global__ void prep_kernel(const float* __restrict__ Wself,
                            const float* __restrict__ Wneigh,
                            const float* __restrict__ b,
                            unsigned short* __restrict__ Wt,
                            float* __restrict__ bsum, int nrel) {
    int idx = blockIdx.x * blockDim.x + threadIdx.x;
    if (idx < DIMC * KCAT) {
        int k = idx & (KCAT - 1);
        int nn = idx >> 9;
        float v;
        if (k < DIMC) {
            v = 0.f;
            for (int r = 0; r < nrel; ++r) v += Wself[r * DIMC * DIMC + k * DIMC + nn];
        } else {
            int r = (k - DIMC) >> 7, kk = (k - DIMC) & 127;
            v = Wneigh[r * DIMC * DIMC + kk * DIMC + nn];
        }
        Wt[idx] = f2bf(v);
    }
    if (idx < DIMC) {
        float s = 0.f;
        for (int r = 0; r < nrel; ++r) s += b[r * DIMC + idx];
        bsum[idx] = s;
    }
}

// -------------------------------------------------------------- convth ----
__global__ void convth_kernel(const float* __restrict__ h,
                              unsigned short* __restrict__ Xcat, int n) {
    int idx = blockIdx.x * blockDim.x + threadIdx.x;
    if (idx >= n * 16) return;
    int r = idx >> 4, c = (idx & 15) << 3;
    const float4* hp = (const float4*)&h[(long long)r * DIMC + c];
    float4 a = hp[0], d = hp[1];
    union { unsigned short s[8]; uint4 v; } o;
    o.s[0] = f2bf(a.x); o.s[1] = f2bf(a.y); o.s[2] = f2bf(a.z); o.s[3] = f2bf(a.w);
    o.s[4] = f2bf(d.x); o.s[5] = f2bf(d.y); o.s[6] = f2bf(d.z); o.s[7] = f2bf(d.w);
    *(uint4*)(Xcat + (long long)r * KCAT + c) = o.v;
}

// -------------------------------------------------------- CSR building ----
__global__ void degcnt_kernel(const int* __restrict__ edst,
                              int* __restrict__ counts, int n, int E) {
    int e = blockIdx.x * blockDim.x + threadIdx.x;
    int rel = blockIdx.y;
    if (e < E) atomicAdd(&counts[(long long)rel * n + edst[(long long)rel * E + e]], 1);
}

__global__ void scan_block_kernel(const int* __restrict__ counts,
                                  int* __restrict__ eprefix,
                                  int* __restrict__ bsums, int total) {
    __shared__ int lds[256];
    int i = blockIdx.x * 256 + threadIdx.x;
    int v = (i < total) ? counts[i] : 0;
    lds[threadIdx.x] = v;
    __syncthreads();
    for (int off = 1; off < 256; off <<= 1) {
        int t = (threadIdx.x >= off) ? lds[threadIdx.x - off] : 0;
        __syncthreads();
        lds[threadIdx.x] += t;
        __syncthreads();
    }
    if (i < total) eprefix[i] = lds[threadIdx.x] - v;    // exclusive
    if (threadIdx.x == 255) bsums[blockIdx.x] = lds[255];
}

__global__ void scan_partials_kernel(int* __restrict__ bsums, int nb) {
    __shared__ int lds[1024];
    int v = (threadIdx.x < nb) ? bsums[threadIdx.x] : 0;
    lds[threadIdx.x] = v;
    __syncthreads();
    for (int off = 1; off < 1024; off <<= 1) {
        int t = (threadIdx.x >= off) ? lds[threadIdx.x - off] : 0;
        __syncthreads();
        lds[threadIdx.x] += t;
        __syncthreads();
    }
    if (threadIdx.x < nb) bsums[threadIdx.x] = lds[threadIdx.x] - v;
}

// rowptr[i] = eprefix[i] + boff[i>>8]; cursor seeded with the same value.
__global__ void finalize_kernel(const int* __restrict__ eprefix,
                                const int* __restrict__ boff,
                                int* __restrict__ rowptr,
                                int* __restrict__ cursor, int nseg, int total) {
    int i = blockIdx.x * blockDim.x + threadIdx.x;
    if (i < nseg) {
        int v = eprefix[i] + boff[i >> 8];
        rowptr[i] = v;
        cursor[i] = v;
    }
    if (i == nseg) rowptr[nseg] = total;
}

__global__ void fill_kernel(const int* __restrict__ esrc,
                            const int* __restrict__ edst,
                            int* __restrict__ cursor,
                            int* __restrict__ colidx, int n, int E) {
    int e = blockIdx.x * blockDim.x + threadIdx.x;
    int rel = blockIdx.y;
    if (e >= E) return;
    int d   = edst[(long long)rel * E + e];
    int pos = atomicAdd(&cursor[rel * n + d], 1);
    colidx[pos] = esrc[(long long)rel * E + e];
}

// -------------------------------------------------------------- gather ----
// One wave per (rel,dst). Lane owns 2 bf16 cols (4B read/row from Xcat's
// self block). 4-wide unrolled row loop for MLP; f32 accumulate; one
// packed-bf16 store into the msg block.
__global__ __launch_bounds__(256) void gather_kernel(
    const unsigned short* Xcat,           // self block read + msg block write
    const int* __restrict__ rowptr,
    const int* __restrict__ colidx,
    int n) {
    int w = threadIdx.x >> 6, lane = threadIdx.x & 63;
    int dst = blockIdx.x * 4 + w;
    int rel = blockIdx.y;
    if (dst >= n) return;
    int idx   = rel * n + dst;
    int start = rowptr[idx];
    int deg   = rowptr[idx + 1] - start;

    float ax0 = 0.f, ay0 = 0.f, ax1 = 0.f, ay1 = 0.f;
    float ax2 = 0.f, ay2 = 0.f, ax3 = 0.f, ay3 = 0.f;
    for (int base = 0; base < deg; base += 64) {
        int m = min(64, deg - base);
        int vidx = (lane < m) ? colidx[start + base + lane] : 0;
        int j = 0;
        for (; j + 3 < m; j += 4) {
            int s0 = __shfl(vidx, j), s1 = __shfl(vidx, j + 1);
            int s2 = __shfl(vidx, j + 2), s3 = __shfl(vidx, j + 3);
            unsigned u0 = *(const unsigned*)&Xcat[(long long)s0 * KCAT + lane * 2];
            unsigned u1 = *(const unsigned*)&Xcat[(long long)s1 * KCAT + lane * 2];
            unsigned u2 = *(const unsigned*)&Xcat[(long long)s2 * KCAT + lane * 2];
            unsigned u3 = *(const unsigned*)&Xcat[(long long)s3 * KCAT + lane * 2];
            float lo, hi;
            bf2x(u0, lo, hi); ax0 += lo; ay0 += hi;
            bf2x(u1, lo, hi); ax1 += lo; ay1 += hi;
            bf2x(u2, lo, hi); ax2 += lo; ay2 += hi;
            bf2x(u3, lo, hi); ax3 += lo; ay3 += hi;
        }
        for (; j < m; ++j) {
            int s0 = __shfl(vidx, j);
            unsigned u0 = *(const unsigned*)&Xcat[(long long)s0 * KCAT + lane * 2];
            float lo, hi;
            bf2x(u0, lo, hi); ax0 += lo; ay0 += hi;
        }
    }
    float sc = (deg > 0) ? (1.0f / (float)deg) : 0.f;
    unsigned p = (unsigned)f2bf((ax0 + ax1 + ax2 + ax3) * sc) |
                 ((unsigned)f2bf((ay0 + ay1 + ay2 + ay3) * sc) << 16);
    *(unsigned*)((unsigned short*)Xcat + (long long)dst * KCAT + DIMC + rel * DIMC + lane * 2) = p;
}

// ---------------------------------------------------------------- gemm ----
// 64x128 tile, BK=64, 4 waves (1x4), 16x16x32 bf16 MFMA. 24 KB LDS ->
// ~4 blocks/CU; grid 782 (vs 391) removes the 1.5-blocks/CU imbalance.
__global__ __launch_bounds__(256) void mfma_gemm_kernel(
    const unsigned short* __restrict__ Xcat,
    const unsigned short* __restrict__ Wt,
    const float* __restrict__ bsum,
    float* __restrict__ out, int n) {
    __shared__ __align__(16) unsigned short As[64 * 64];    // 8 KB
    __shared__ __align__(16) unsigned short Bs[128 * 64];   // 16 KB

    const int tid = threadIdx.x;
    const int w   = tid >> 6;
    const int l   = tid & 63;
    const long long row0 = (long long)blockIdx.x * 64;

    const int lrow8 = l >> 3;
    const int scol  = (((l & 7) ^ lrow8) << 4);

    f32x4 zero4 = {0.f, 0.f, 0.f, 0.f};
    f32x4 acc[4][2];
#pragma unroll
    for (int m = 0; m < 4; ++m)
#pragma unroll
        for (int q = 0; q < 2; ++q) acc[m][q] = zero4;

    for (int kt = 0; kt < 8; ++kt) {
#pragma unroll
        for (int j = 0; j < 2; ++j) {            // As: 8 x 1KB chunks
            int ch = w * 2 + j;
            int r  = ch * 8 + lrow8;             // 0..63
            gload_lds16((const char*)Xcat + (row0 + r) * (KCAT * 2) + kt * 128 + scol,
                        (char*)As + ch * 1024);
        }
#pragma unroll
        for (int j = 0; j < 4; ++j) {            // Bs: 16 x 1KB chunks
            int ch = w * 4 + j;
            int r  = ch * 8 + lrow8;             // 0..127
            gload_lds16((const char*)Wt + (long long)r * (KCAT * 2) + kt * 128 + scol,
                        (char*)Bs + ch * 1024);
        }
        __syncthreads();

        bf16x8 af[4][2], bfr[2][2];
#pragma unroll
        for (int m = 0; m < 4; ++m)
#pragma unroll
            for (int ks = 0; ks < 2; ++ks) {
                int lr = m * 16 + (l & 15);
                int cb = ks * 64 + ((l >> 4) << 4);
                af[m][ks] = *(const bf16x8*)((const char*)As + lr * 128 + (cb ^ ((lr & 7) << 4)));
            }
#pragma unroll
        for (int q = 0; q < 2; ++q)
#pragma unroll
            for (int ks = 0; ks < 2; ++ks) {
                int br = w * 32 + q * 16 + (l & 15);
                int cb = ks * 64 + ((l >> 4) << 4);
                bfr[q][ks] = *(const bf16x8*)((const char*)Bs + br * 128 + (cb ^ ((br & 7) << 4)));
            }
#pragma unroll
        for (int m = 0; m < 4; ++m)
#pragma unroll
            for (int q = 0; q < 2; ++q)
#pragma unroll
                for (int ks = 0; ks < 2; ++ks)
                    acc[m][q] = __builtin_amdgcn_mfma_f32_16x16x32_bf16(
                        af[m][ks], bfr[q][ks], acc[m][q], 0, 0, 0);
        __syncthreads();
    }

#pragma unroll
    for (int q = 0; q < 2; ++q) {
        int ccol = w * 32 + q * 16 + (l & 15);
        float bb = bsum[ccol];
#pragma unroll
        for (int m = 0; m < 4; ++m) {
            long long crow = row0 + m * 16 + ((l >> 4) << 2);
#pragma unroll
            for (int j2 = 0; j2 < 4; ++j2) {
                long long gr = crow + j2;
                if (gr < n) out[gr * DIMC + ccol] = acc[m][q][j2] + bb;
            }
        }
    }
}

// -------------------------------------------------------------- launch ----
extern "C" void kernel_launch(void* const* d_in, const int* in_sizes, int n_in,
                              void* d_out, int out_size, void* d_ws, size_t ws_size,
                              hipStream_t stream) {
    const float* h      = (const float*)d_in[0];
    const float* Wself  = (const float*)d_in[1];
    const float* Wneigh = (const float*)d_in[2];
    const float* b      = (const float*)d_in[3];
    const int*   esrc   = (const int*)d_in[4];
    const int*   edst   = (const int*)d_in[5];

    const int n    = in_sizes[0] / DIMC;                 // 50000
    const int nrel = in_sizes[1] / (DIMC * DIMC);        // 3
    const int E    = in_sizes[4] / nrel;                 // 200000

    const int Mpad = ((n + 127) / 128) * 128;            // 50048 (782 * 64)
    const int nseg = nrel * n;                           // 150000
    const int NB   = (nseg + 255) / 256;                 // <= 1024

    char* ws = (char*)d_ws;
    size_t off = 0;
    unsigned short* Xcat = (unsigned short*)(ws + off); off += (size_t)Mpad * KCAT * 2;
    unsigned short* Wt   = (unsigned short*)(ws + off); off += (size_t)DIMC * KCAT * 2;
    float* bsum          = (float*)(ws + off);          off += DIMC * sizeof(float);
    int* counts          = (int*)(ws + off);            off += (size_t)nseg * 4;
    int* eprefix         = (int*)(ws + off);            off += (size_t)nseg * 4;
    int* boff            = (int*)(ws + off);            off += 1024 * 4;
    int* rowptr          = (int*)(ws + off);            off += ((size_t)nseg + 1) * 4;
    int* cursor          = (int*)(ws + off);            off += (size_t)nseg * 4;
    int* colidx          = (int*)(ws + off);            off += (size_t)nrel * E * 4;

    hipMemsetAsync(counts, 0, (size_t)nseg * 4, stream);

    prep_kernel<<<dim3((DIMC * KCAT + 255) / 256), dim3(256), 0, stream>>>(
        Wself, Wneigh, b, Wt, bsum, nrel);
    convth_kernel<<<dim3((n * 16 + 255) / 256), dim3(256), 0, stream>>>(h, Xcat, n);
    degcnt_kernel<<<dim3((E + 255) / 256, nrel), dim3(256), 0, stream>>>(
        edst, counts, n, E);
    scan_block_kernel<<<dim3(NB), dim3(256), 0, stream>>>(counts, eprefix, boff, nseg);
    scan_partials_kernel<<<dim3(1), dim3(1024), 0, stream>>>(boff, NB);
    finalize_kernel<<<dim3((nseg + 256) / 256), dim3(256), 0, stream>>>(
        eprefix, boff, rowptr, cursor, nseg, nrel * E);
    fill_kernel<<<dim3((E + 255) / 256, nrel), dim3(256), 0, stream>>>(
        esrc, edst, cursor, colidx, n, E);
    gather_kernel<<<dim3((n + 3) / 4, nrel), dim3(256), 0, stream>>>(
        Xcat, rowptr, colidx, n);
    mfma_gemm_kernel<<<dim3((n + 63) / 64), dim3(256), 0, stream>>>(
        Xcat, Wt, bsum, (float*)d_out, n);
}